// Round 1
// baseline (1287.513 us; speedup 1.0000x reference)
//
#include <hip/hip_runtime.h>
#include <math.h>

#define T_STEPS 120
#define BATCH   1024

// One block owns NB batch rows for the whole T-step scan.
// Thread j holds column j of [W;U] in registers (K = DIN+U floats).
// Per step: stage x_t in LDS -> z[j] = b[j] + sum_k xh[k]*wcol[k] -> LDS ->
// gate-combine (thread j == (batch j/U, unit j%U), c in a register) -> h to LDS.
template<int DIN, int U, int NB>
__global__ __launch_bounds__(4*U, 2)
void lstm_scan(const float* __restrict__ xin,   // (B,T,DIN)
               const float* __restrict__ W,     // (DIN,4U) row-major
               const float* __restrict__ Uw,    // (U,4U)   row-major
               const float* __restrict__ bias,  // (4U)
               float* __restrict__ hout,        // (B,T,U) or (B,U) if last_only
               int last_only)
{
    constexpr int TPB  = 4 * U;          // one thread per z column
    constexpr int K    = DIN + U;        // combined input length
    constexpr int XCNT = NB * DIN;       // floats staged per step
    constexpr int PRE  = (XCNT + TPB - 1) / TPB;

    static_assert(NB * U == TPB, "gate threads must cover block");
    static_assert((K % 4) == 0, "float4 inner loop");

    __shared__ __align__(16) float xh[NB][K];       // [x_t | h]
    __shared__ __align__(16) float zbuf[NB][4 * U];

    const int j  = threadIdx.x;
    const int b0 = blockIdx.x * NB;

    // ---- one-time: weight column j into registers (coalesced across lanes) ----
    float wcol[K];
#pragma unroll
    for (int k = 0; k < DIN; ++k) wcol[k] = W[k * (4 * U) + j];
#pragma unroll
    for (int k = 0; k < U; ++k)   wcol[DIN + k] = Uw[k * (4 * U) + j];
    const float breg = bias[j];

    // gate-thread identity: batch bi_g, hidden unit un_g
    const int bi_g = j / U;
    const int un_g = j % U;
    float creg = 0.f;

    // init h region of LDS
    xh[bi_g][DIN + un_g] = 0.f;

    // prefetch x for t=0
    float xpre[PRE];
#pragma unroll
    for (int p = 0; p < PRE; ++p) {
        int idx = j + p * TPB;
        if (idx < XCNT) {
            int bi = idx / DIN, k = idx % DIN;
            xpre[p] = xin[((size_t)(b0 + bi) * T_STEPS + 0) * DIN + k];
        }
    }

    for (int t = 0; t < T_STEPS; ++t) {
        __syncthreads();   // prev-step xh reads done; h-writes visible
#pragma unroll
        for (int p = 0; p < PRE; ++p) {
            int idx = j + p * TPB;
            if (idx < XCNT) xh[idx / DIN][idx % DIN] = xpre[p];
        }
        __syncthreads();   // staging visible

        // prefetch next x_t (overlaps FMA loop below)
        if (t + 1 < T_STEPS) {
#pragma unroll
            for (int p = 0; p < PRE; ++p) {
                int idx = j + p * TPB;
                if (idx < XCNT) {
                    int bi = idx / DIN, k = idx % DIN;
                    xpre[p] = xin[((size_t)(b0 + bi) * T_STEPS + (t + 1)) * DIN + k];
                }
            }
        }

        // ---- z = [x_t, h] @ wcol + b, for NB batch rows ----
        float acc[NB];
#pragma unroll
        for (int bi = 0; bi < NB; ++bi) acc[bi] = breg;
#pragma unroll
        for (int k4 = 0; k4 < K / 4; ++k4) {
#pragma unroll
            for (int bi = 0; bi < NB; ++bi) {
                float4 v = reinterpret_cast<const float4*>(&xh[bi][0])[k4];
                acc[bi] = fmaf(v.x, wcol[4 * k4 + 0], acc[bi]);
                acc[bi] = fmaf(v.y, wcol[4 * k4 + 1], acc[bi]);
                acc[bi] = fmaf(v.z, wcol[4 * k4 + 2], acc[bi]);
                acc[bi] = fmaf(v.w, wcol[4 * k4 + 3], acc[bi]);
            }
        }
#pragma unroll
        for (int bi = 0; bi < NB; ++bi) zbuf[bi][j] = acc[bi];
        __syncthreads();   // zbuf visible

        // ---- gates: i,f,g,o = z[un], z[un+U], z[un+2U], z[un+3U] ----
        {
            float zi = zbuf[bi_g][un_g];
            float zf = zbuf[bi_g][un_g + U];
            float zg = zbuf[bi_g][un_g + 2 * U];
            float zo = zbuf[bi_g][un_g + 3 * U];
            float si = 1.f / (1.f + expf(-zi));
            float sf = 1.f / (1.f + expf(-zf));
            float so = 1.f / (1.f + expf(-zo));
            float g  = fmaxf(zg, 0.f);
            float c  = sf * creg + si * g;
            creg = c;
            float h  = so * fmaxf(c, 0.f);
            xh[bi_g][DIN + un_g] = h;
            if (!last_only) {
                hout[((size_t)(b0 + bi_g) * T_STEPS + t) * U + un_g] = h;
            } else if (t == T_STEPS - 1) {
                hout[(size_t)(b0 + bi_g) * U + un_g] = h;
            }
        }
    }
}

// Dense head: one wave per batch row. 64 ->relu-> 64 ->relu-> 32 -> 101 -> softmax
__global__ __launch_bounds__(256)
void dense_head(const float* __restrict__ h3,    // (B,64)
                const float* __restrict__ Wd1, const float* __restrict__ bd1,
                const float* __restrict__ Wd2, const float* __restrict__ bd2,
                const float* __restrict__ Wd3, const float* __restrict__ bd3,
                float* __restrict__ out)         // (B,101)
{
    __shared__ float s1[4][64];
    __shared__ float s2[4][32];
    const int w    = threadIdx.x >> 6;
    const int lane = threadIdx.x & 63;
    const int row  = blockIdx.x * 4 + w;

    float hval = h3[(size_t)row * 64 + lane];
    float a = bd1[lane];
#pragma unroll
    for (int k = 0; k < 64; ++k) {
        float hk = __shfl(hval, k, 64);
        a = fmaf(hk, Wd1[k * 64 + lane], a);
    }
    s1[w][lane] = fmaxf(a, 0.f);
    __syncthreads();

    if (lane < 32) {
        float a2 = bd2[lane];
#pragma unroll
        for (int k = 0; k < 64; ++k) a2 = fmaf(s1[w][k], Wd2[k * 32 + lane], a2);
        s2[w][lane] = fmaxf(a2, 0.f);
    }
    __syncthreads();

    float a0 = bd3[lane];
#pragma unroll
    for (int k = 0; k < 32; ++k) a0 = fmaf(s2[w][k], Wd3[k * 101 + lane], a0);
    float a1 = -INFINITY;
    if (lane < 37) {
        a1 = bd3[64 + lane];
#pragma unroll
        for (int k = 0; k < 32; ++k) a1 = fmaf(s2[w][k], Wd3[k * 101 + 64 + lane], a1);
    }

    float m = fmaxf(a0, a1);
#pragma unroll
    for (int off = 32; off > 0; off >>= 1) m = fmaxf(m, __shfl_xor(m, off, 64));
    float e0 = expf(a0 - m);
    float e1 = (lane < 37) ? expf(a1 - m) : 0.f;
    float s = e0 + e1;
#pragma unroll
    for (int off = 32; off > 0; off >>= 1) s += __shfl_xor(s, off, 64);

    out[(size_t)row * 101 + lane] = e0 / s;
    if (lane < 37) out[(size_t)row * 101 + 64 + lane] = e1 / s;
}

extern "C" void kernel_launch(void* const* d_in, const int* in_sizes, int n_in,
                              void* d_out, int out_size, void* d_ws, size_t ws_size,
                              hipStream_t stream) {
    const float* x   = (const float*)d_in[0];
    const float* W1  = (const float*)d_in[1];
    const float* U1  = (const float*)d_in[2];
    const float* b1  = (const float*)d_in[3];
    const float* W2  = (const float*)d_in[4];
    const float* U2  = (const float*)d_in[5];
    const float* b2  = (const float*)d_in[6];
    const float* W3  = (const float*)d_in[7];
    const float* U3  = (const float*)d_in[8];
    const float* b3  = (const float*)d_in[9];
    const float* Wd1 = (const float*)d_in[10];
    const float* bd1 = (const float*)d_in[11];
    const float* Wd2 = (const float*)d_in[12];
    const float* bd2 = (const float*)d_in[13];
    const float* Wd3 = (const float*)d_in[14];
    const float* bd3 = (const float*)d_in[15];

    float* h1 = (float*)d_ws;                                  // 1024*120*64
    float* h2 = h1 + (size_t)BATCH * T_STEPS * 64;             // 1024*120*128
    float* h3 = h2 + (size_t)BATCH * T_STEPS * 128;            // 1024*64

    lstm_scan<132, 64, 4><<<BATCH / 4, 256, 0, stream>>>(x,  W1, U1, b1, h1, 0);
    lstm_scan<64, 128, 4><<<BATCH / 4, 512, 0, stream>>>(h1, W2, U2, b2, h2, 0);
    lstm_scan<128, 64, 4><<<BATCH / 4, 256, 0, stream>>>(h2, W3, U3, b3, h3, 1);
    dense_head<<<BATCH / 4, 256, 0, stream>>>(h3, Wd1, bd1, Wd2, bd2, Wd3, bd3,
                                              (float*)d_out);
}

// Round 2
// 1062.783 us; speedup vs baseline: 1.2115x; 1.2115x over previous
//
#include <hip/hip_runtime.h>
#include <math.h>

#define T_STEPS 120
#define BATCH   1024

// ---------------------------------------------------------------------------
// GEMM: C[m,n] = sum_k A'[m,k] * Bw[k,n], where A' row m maps to a time-chunk
// of a (B, T, K) tensor: b = m/TC, t = t0 + m%TC. C is compact (B, TC, N).
// BM=128, BN=64, BK=32, 256 threads, 8x4 micro-tile per thread.
// ---------------------------------------------------------------------------
__global__ __launch_bounds__(256, 2)
void gemm_xz(const float* __restrict__ A,   // (B, T, K)
             const float* __restrict__ Bw,  // (K, N)
             float* __restrict__ C,         // (B, TC, N)
             int N, int K, int TC, int t0)
{
    constexpr int BM = 128, BN = 64, BK = 32;
    __shared__ __align__(16) float As[BK][BM + 4];   // +4 pad keeps 16B align
    __shared__ __align__(16) float Bs[BK][BN];

    const int tid = threadIdx.x;
    const int tn = tid & 15;        // 16 threads along N (4 cols each)
    const int tm = tid >> 4;        // 16 threads along M (8 rows each)
    const int m0 = blockIdx.x * BM;
    const int n0 = blockIdx.y * BN;

    float acc[8][4];
#pragma unroll
    for (int r = 0; r < 8; ++r)
#pragma unroll
        for (int c = 0; c < 4; ++c) acc[r][c] = 0.f;

    const int ntiles = (K + BK - 1) / BK;
    for (int kt = 0; kt < ntiles; ++kt) {
        const int kbase = kt * BK;
        __syncthreads();
        // stage A tile (transposed): 128 rows x 32 k
#pragma unroll
        for (int p = 0; p < 4; ++p) {
            int flat = tid + p * 256;
            int r = flat >> 3, c4 = flat & 7;
            int kidx = kbase + c4 * 4;
            float4 v = make_float4(0.f, 0.f, 0.f, 0.f);
            if (kidx < K) {                      // K is always a multiple of 4
                int gm = m0 + r;
                int b = gm / TC;
                int t = t0 + (gm - b * TC);
                v = *reinterpret_cast<const float4*>(
                        &A[((size_t)b * T_STEPS + t) * K + kidx]);
            }
            As[c4 * 4 + 0][r] = v.x;
            As[c4 * 4 + 1][r] = v.y;
            As[c4 * 4 + 2][r] = v.z;
            As[c4 * 4 + 3][r] = v.w;
        }
        // stage B tile: 32 k x 64 n
#pragma unroll
        for (int p = 0; p < 2; ++p) {
            int flat = tid + p * 256;
            int kr = flat >> 4, c4 = flat & 15;
            float4 v = make_float4(0.f, 0.f, 0.f, 0.f);
            if (kbase + kr < K)
                v = *reinterpret_cast<const float4*>(
                        &Bw[(size_t)(kbase + kr) * N + n0 + c4 * 4]);
            *reinterpret_cast<float4*>(&Bs[kr][c4 * 4]) = v;
        }
        __syncthreads();

#pragma unroll 8
        for (int k = 0; k < BK; ++k) {
            float4 a0 = *reinterpret_cast<const float4*>(&As[k][tm * 8]);
            float4 a1 = *reinterpret_cast<const float4*>(&As[k][tm * 8 + 4]);
            float4 bb = *reinterpret_cast<const float4*>(&Bs[k][tn * 4]);
            float av[8] = {a0.x, a0.y, a0.z, a0.w, a1.x, a1.y, a1.z, a1.w};
            float bv[4] = {bb.x, bb.y, bb.z, bb.w};
#pragma unroll
            for (int r = 0; r < 8; ++r)
#pragma unroll
                for (int c = 0; c < 4; ++c)
                    acc[r][c] = fmaf(av[r], bv[c], acc[r][c]);
        }
    }

#pragma unroll
    for (int r = 0; r < 8; ++r) {
        int gm = m0 + tm * 8 + r;
        int b = gm / TC;
        int tl = gm - b * TC;
        float4 o = make_float4(acc[r][0], acc[r][1], acc[r][2], acc[r][3]);
        *reinterpret_cast<float4*>(&C[((size_t)b * TC + tl) * N + n0 + tn * 4]) = o;
    }
}

// ---------------------------------------------------------------------------
// Recurrent-only scan: z = xz_t + h @ Uw + b, gates, over a time chunk.
// Thread j holds column j of Uw (U floats, register-resident, no spill).
// NB batch rows per block; c/h state persisted to global between chunks.
// ---------------------------------------------------------------------------
template<int U, int NB>
__global__ __launch_bounds__(4 * U, 2)
void lstm_rec(const float* __restrict__ xz,    // (B, TC, 4U) chunk
              const float* __restrict__ Uw,    // (U, 4U)
              const float* __restrict__ bias,  // (4U)
              float* __restrict__ hout,        // (B,T,U) or (B,U) if last_only
              float* __restrict__ cst,         // (B,U)
              float* __restrict__ hst,         // (B,U)
              int TC, int t0, int last_only)
{
    constexpr int TPB = 4 * U;
    const int j  = threadIdx.x;
    const int b0 = blockIdx.x * NB;

    __shared__ __align__(16) float hsh[NB][U];
    __shared__ float zbuf[NB][TPB];

    float wcol[U];
#pragma unroll
    for (int k = 0; k < U; ++k) wcol[k] = Uw[k * TPB + j];
    const float breg = bias[j];

    const bool gt = (j < NB * U);
    const int bi_g = j / U, un_g = j % U;
    float creg = 0.f;
    if (gt) {
        float h0 = 0.f;
        if (t0 != 0) {
            creg = cst[(size_t)(b0 + bi_g) * U + un_g];
            h0   = hst[(size_t)(b0 + bi_g) * U + un_g];
        }
        hsh[bi_g][un_g] = h0;
    }

    float xzv[NB];
#pragma unroll
    for (int bi = 0; bi < NB; ++bi)
        xzv[bi] = xz[((size_t)(b0 + bi) * TC + 0) * TPB + j];

    for (int t = 0; t < TC; ++t) {
        __syncthreads();                    // h writes (or init) visible
        float acc[NB];
#pragma unroll
        for (int bi = 0; bi < NB; ++bi) acc[bi] = breg + xzv[bi];
        if (t + 1 < TC) {                   // prefetch next xz under the FMAs
#pragma unroll
            for (int bi = 0; bi < NB; ++bi)
                xzv[bi] = xz[((size_t)(b0 + bi) * TC + (t + 1)) * TPB + j];
        }
#pragma unroll
        for (int k4 = 0; k4 < U / 4; ++k4) {
#pragma unroll
            for (int bi = 0; bi < NB; ++bi) {
                float4 v = reinterpret_cast<const float4*>(&hsh[bi][0])[k4];
                acc[bi] = fmaf(v.x, wcol[4 * k4 + 0], acc[bi]);
                acc[bi] = fmaf(v.y, wcol[4 * k4 + 1], acc[bi]);
                acc[bi] = fmaf(v.z, wcol[4 * k4 + 2], acc[bi]);
                acc[bi] = fmaf(v.w, wcol[4 * k4 + 3], acc[bi]);
            }
        }
#pragma unroll
        for (int bi = 0; bi < NB; ++bi) zbuf[bi][j] = acc[bi];
        __syncthreads();                    // zbuf visible
        if (gt) {
            float zi = zbuf[bi_g][un_g];
            float zf = zbuf[bi_g][un_g + U];
            float zg = zbuf[bi_g][un_g + 2 * U];
            float zo = zbuf[bi_g][un_g + 3 * U];
            float si = 1.f / (1.f + expf(-zi));
            float sf = 1.f / (1.f + expf(-zf));
            float so = 1.f / (1.f + expf(-zo));
            float c  = sf * creg + si * fmaxf(zg, 0.f);
            creg = c;
            float h  = so * fmaxf(c, 0.f);
            hsh[bi_g][un_g] = h;
            if (!last_only)
                hout[((size_t)(b0 + bi_g) * T_STEPS + (t0 + t)) * U + un_g] = h;
            else if (t0 + t == T_STEPS - 1)
                hout[(size_t)(b0 + bi_g) * U + un_g] = h;
        }
    }
    if (gt) {
        cst[(size_t)(b0 + bi_g) * U + un_g] = creg;
        hst[(size_t)(b0 + bi_g) * U + un_g] = hsh[bi_g][un_g];
    }
}

// Dense head: one wave per batch row. 64 ->relu-> 64 ->relu-> 32 -> 101 -> softmax
__global__ __launch_bounds__(256)
void dense_head(const float* __restrict__ h3,    // (B,64)
                const float* __restrict__ Wd1, const float* __restrict__ bd1,
                const float* __restrict__ Wd2, const float* __restrict__ bd2,
                const float* __restrict__ Wd3, const float* __restrict__ bd3,
                float* __restrict__ out)         // (B,101)
{
    __shared__ float s1[4][64];
    __shared__ float s2[4][32];
    const int w    = threadIdx.x >> 6;
    const int lane = threadIdx.x & 63;
    const int row  = blockIdx.x * 4 + w;

    float hval = h3[(size_t)row * 64 + lane];
    float a = bd1[lane];
#pragma unroll
    for (int k = 0; k < 64; ++k) {
        float hk = __shfl(hval, k, 64);
        a = fmaf(hk, Wd1[k * 64 + lane], a);
    }
    s1[w][lane] = fmaxf(a, 0.f);
    __syncthreads();

    if (lane < 32) {
        float a2 = bd2[lane];
#pragma unroll
        for (int k = 0; k < 64; ++k) a2 = fmaf(s1[w][k], Wd2[k * 32 + lane], a2);
        s2[w][lane] = fmaxf(a2, 0.f);
    }
    __syncthreads();

    float a0 = bd3[lane];
#pragma unroll
    for (int k = 0; k < 32; ++k) a0 = fmaf(s2[w][k], Wd3[k * 101 + lane], a0);
    float a1 = -INFINITY;
    if (lane < 37) {
        a1 = bd3[64 + lane];
#pragma unroll
        for (int k = 0; k < 32; ++k) a1 = fmaf(s2[w][k], Wd3[k * 101 + 64 + lane], a1);
    }

    float m = fmaxf(a0, a1);
#pragma unroll
    for (int off = 32; off > 0; off >>= 1) m = fmaxf(m, __shfl_xor(m, off, 64));
    float e0 = expf(a0 - m);
    float e1 = (lane < 37) ? expf(a1 - m) : 0.f;
    float s = e0 + e1;
#pragma unroll
    for (int off = 32; off > 0; off >>= 1) s += __shfl_xor(s, off, 64);

    out[(size_t)row * 101 + lane] = e0 / s;
    if (lane < 37) out[(size_t)row * 101 + 64 + lane] = e1 / s;
}

extern "C" void kernel_launch(void* const* d_in, const int* in_sizes, int n_in,
                              void* d_out, int out_size, void* d_ws, size_t ws_size,
                              hipStream_t stream) {
    const float* x   = (const float*)d_in[0];
    const float* W1  = (const float*)d_in[1];
    const float* U1  = (const float*)d_in[2];
    const float* b1  = (const float*)d_in[3];
    const float* W2  = (const float*)d_in[4];
    const float* U2  = (const float*)d_in[5];
    const float* b2  = (const float*)d_in[6];
    const float* W3  = (const float*)d_in[7];
    const float* U3  = (const float*)d_in[8];
    const float* b3  = (const float*)d_in[9];
    const float* Wd1 = (const float*)d_in[10];
    const float* bd1 = (const float*)d_in[11];
    const float* Wd2 = (const float*)d_in[12];
    const float* bd2 = (const float*)d_in[13];
    const float* Wd3 = (const float*)d_in[14];
    const float* bd3 = (const float*)d_in[15];

    // workspace layout (floats); peak ~160 MB
    float* xzbuf = (float*)d_ws;                      // 1024*60*256 = 15728640 (max chunk)
    float* h1  = xzbuf + 15728640;                    // 1024*120*64 = 7864320
    float* h2  = h1 + 7864320;                        // 1024*120*128 = 15728640
    float* h3  = h2 + 15728640;                       // 1024*64
    float* c1  = h3 + 65536;
    float* hs1 = c1 + 65536;
    float* c2  = hs1 + 65536;                         // 1024*128
    float* hs2 = c2 + 131072;
    float* c3  = hs2 + 131072;
    float* hs3 = c3 + 65536;

    // Layer 1: K=132 -> 4U=256, time chunks of 60
    for (int ch = 0; ch < 2; ++ch) {
        gemm_xz<<<dim3(480, 4), 256, 0, stream>>>(x, W1, xzbuf, 256, 132, 60, ch * 60);
        lstm_rec<64, 2><<<512, 256, 0, stream>>>(xzbuf, U1, b1, h1, c1, hs1, 60, ch * 60, 0);
    }
    // Layer 2: K=64 -> 4U=512, time chunks of 30
    for (int ch = 0; ch < 4; ++ch) {
        gemm_xz<<<dim3(240, 8), 256, 0, stream>>>(h1, W2, xzbuf, 512, 64, 30, ch * 30);
        lstm_rec<128, 2><<<512, 512, 0, stream>>>(xzbuf, U2, b2, h2, c2, hs2, 30, ch * 30, 0);
    }
    // Layer 3: K=128 -> 4U=256, time chunks of 60, last hidden only
    for (int ch = 0; ch < 2; ++ch) {
        gemm_xz<<<dim3(480, 4), 256, 0, stream>>>(h2, W3, xzbuf, 256, 128, 60, ch * 60);
        lstm_rec<64, 2><<<512, 256, 0, stream>>>(xzbuf, U3, b3, h3, c3, hs3, 60, ch * 60, 1);
    }
    dense_head<<<256, 256, 0, stream>>>(h3, Wd1, bd1, Wd2, bd2, Wd3, bd3, (float*)d_out);
}

// Round 3
// 986.510 us; speedup vs baseline: 1.3051x; 1.0773x over previous
//
#include <hip/hip_runtime.h>
#include <math.h>

#define T_STEPS 120
#define BATCH   1024

// ---------------------------------------------------------------------------
// GEMM: C[m,n] = sum_k A'[m,k] * Bw[k,n], where A' row m maps to a time-chunk
// of a (B, T, K) tensor: b = m/TC, t = t0 + m%TC. C is compact (B, TC, N).
// BM=128, BN=64, BK=32, 256 threads, 8x4 micro-tile per thread.
// ---------------------------------------------------------------------------
__global__ __launch_bounds__(256, 2)
void gemm_xz(const float* __restrict__ A,   // (B, T, K)
             const float* __restrict__ Bw,  // (K, N)
             float* __restrict__ C,         // (B, TC, N)
             int N, int K, int TC, int t0)
{
    constexpr int BM = 128, BN = 64, BK = 32;
    __shared__ __align__(16) float As[BK][BM + 4];
    __shared__ __align__(16) float Bs[BK][BN];

    const int tid = threadIdx.x;
    const int tn = tid & 15;
    const int tm = tid >> 4;
    const int m0 = blockIdx.x * BM;
    const int n0 = blockIdx.y * BN;

    float acc[8][4];
#pragma unroll
    for (int r = 0; r < 8; ++r)
#pragma unroll
        for (int c = 0; c < 4; ++c) acc[r][c] = 0.f;

    const int ntiles = (K + BK - 1) / BK;
    for (int kt = 0; kt < ntiles; ++kt) {
        const int kbase = kt * BK;
        __syncthreads();
#pragma unroll
        for (int p = 0; p < 4; ++p) {
            int flat = tid + p * 256;
            int r = flat >> 3, c4 = flat & 7;
            int kidx = kbase + c4 * 4;
            float4 v = make_float4(0.f, 0.f, 0.f, 0.f);
            if (kidx < K) {
                int gm = m0 + r;
                int b = gm / TC;
                int t = t0 + (gm - b * TC);
                v = *reinterpret_cast<const float4*>(
                        &A[((size_t)b * T_STEPS + t) * K + kidx]);
            }
            As[c4 * 4 + 0][r] = v.x;
            As[c4 * 4 + 1][r] = v.y;
            As[c4 * 4 + 2][r] = v.z;
            As[c4 * 4 + 3][r] = v.w;
        }
#pragma unroll
        for (int p = 0; p < 2; ++p) {
            int flat = tid + p * 256;
            int kr = flat >> 4, c4 = flat & 15;
            float4 v = make_float4(0.f, 0.f, 0.f, 0.f);
            if (kbase + kr < K)
                v = *reinterpret_cast<const float4*>(
                        &Bw[(size_t)(kbase + kr) * N + n0 + c4 * 4]);
            *reinterpret_cast<float4*>(&Bs[kr][c4 * 4]) = v;
        }
        __syncthreads();

#pragma unroll 8
        for (int k = 0; k < BK; ++k) {
            float4 a0 = *reinterpret_cast<const float4*>(&As[k][tm * 8]);
            float4 a1 = *reinterpret_cast<const float4*>(&As[k][tm * 8 + 4]);
            float4 bb = *reinterpret_cast<const float4*>(&Bs[k][tn * 4]);
            float av[8] = {a0.x, a0.y, a0.z, a0.w, a1.x, a1.y, a1.z, a1.w};
            float bv[4] = {bb.x, bb.y, bb.z, bb.w};
#pragma unroll
            for (int r = 0; r < 8; ++r)
#pragma unroll
                for (int c = 0; c < 4; ++c)
                    acc[r][c] = fmaf(av[r], bv[c], acc[r][c]);
        }
    }

#pragma unroll
    for (int r = 0; r < 8; ++r) {
        int gm = m0 + tm * 8 + r;
        int b = gm / TC;
        int tl = gm - b * TC;
        float4 o = make_float4(acc[r][0], acc[r][1], acc[r][2], acc[r][3]);
        *reinterpret_cast<float4*>(&C[((size_t)b * TC + tl) * N + n0 + tn * 4]) = o;
    }
}

// ---------------------------------------------------------------------------
// Recurrent scan: z = xz_t + h @ Uw + b. Thread (kh, j) owns a 64-row slice
// of column j of Uw, held in 16 float4 registers (static indexing only).
// KSPLIT partial sums meet in zbuf; gate threads combine, update c (register),
// write h. NB batch rows per block.
// ---------------------------------------------------------------------------
template<int U, int KSPLIT, int NB>
__global__ __launch_bounds__(4 * U * KSPLIT, 4)
void lstm_rec(const float* __restrict__ xz,    // (B, TC, 4U) chunk
              const float* __restrict__ Uw,    // (U, 4U)
              const float* __restrict__ bias,  // (4U)
              float* __restrict__ hout,        // (B,T,U) or (B,U) if last_only
              float* __restrict__ cst,         // (B,U)
              float* __restrict__ hst,         // (B,U)
              int TC, int t0, int last_only)
{
    constexpr int NZ  = 4 * U;           // z columns
    constexpr int TPB = NZ * KSPLIT;
    constexpr int KCH = U / KSPLIT;      // 64 always
    static_assert(KCH == 64, "weight slice must be 64 floats");

    const int tid = threadIdx.x;
    const int j   = tid & (NZ - 1);
    const int kh  = tid / NZ;
    const int b0  = blockIdx.x * NB;

    __shared__ __align__(16) float hsh[NB][U];
    __shared__ float zbuf[KSPLIT][NB][NZ];

    // weight slice: rows kh*KCH..+63 of column j  (16 float4, static idx)
    float4 wc[16];
#pragma unroll
    for (int q = 0; q < 16; ++q) {
        wc[q].x = Uw[(size_t)(kh * KCH + 4 * q + 0) * NZ + j];
        wc[q].y = Uw[(size_t)(kh * KCH + 4 * q + 1) * NZ + j];
        wc[q].z = Uw[(size_t)(kh * KCH + 4 * q + 2) * NZ + j];
        wc[q].w = Uw[(size_t)(kh * KCH + 4 * q + 3) * NZ + j];
    }
    const float breg = bias[j];

    const bool gt = (tid < NB * U);      // gate threads (subset of kh==0)
    const int bi_g = tid / U;
    const int un_g = tid & (U - 1);
    float creg = 0.f;
    if (gt) {
        float h0 = 0.f;
        if (t0 != 0) {
            creg = cst[(size_t)(b0 + bi_g) * U + un_g];
            h0   = hst[(size_t)(b0 + bi_g) * U + un_g];
        }
        hsh[bi_g][un_g] = h0;
    }

    float xzv[NB];
    if (kh == 0) {
#pragma unroll
        for (int bi = 0; bi < NB; ++bi)
            xzv[bi] = xz[((size_t)(b0 + bi) * TC + 0) * NZ + j];
    }

    for (int t = 0; t < TC; ++t) {
        __syncthreads();                 // hsh (and zbuf gate-reads) settled
        float acc[NB];
#pragma unroll
        for (int bi = 0; bi < NB; ++bi)
            acc[bi] = (kh == 0) ? (breg + xzv[bi]) : 0.f;
        if (kh == 0 && t + 1 < TC) {     // prefetch next xz under the FMAs
#pragma unroll
            for (int bi = 0; bi < NB; ++bi)
                xzv[bi] = xz[((size_t)(b0 + bi) * TC + (t + 1)) * NZ + j];
        }
#pragma unroll
        for (int q = 0; q < 16; ++q) {
#pragma unroll
            for (int bi = 0; bi < NB; ++bi) {
                float4 h4 = *reinterpret_cast<const float4*>(&hsh[bi][kh * KCH + 4 * q]);
                acc[bi] = fmaf(h4.x, wc[q].x, acc[bi]);
                acc[bi] = fmaf(h4.y, wc[q].y, acc[bi]);
                acc[bi] = fmaf(h4.z, wc[q].z, acc[bi]);
                acc[bi] = fmaf(h4.w, wc[q].w, acc[bi]);
            }
        }
#pragma unroll
        for (int bi = 0; bi < NB; ++bi) zbuf[kh][bi][j] = acc[bi];
        __syncthreads();                 // partials visible
        if (gt) {
            float zi = zbuf[0][bi_g][un_g];
            float zf = zbuf[0][bi_g][un_g + U];
            float zg = zbuf[0][bi_g][un_g + 2 * U];
            float zo = zbuf[0][bi_g][un_g + 3 * U];
            if constexpr (KSPLIT == 2) {
                zi += zbuf[1][bi_g][un_g];
                zf += zbuf[1][bi_g][un_g + U];
                zg += zbuf[1][bi_g][un_g + 2 * U];
                zo += zbuf[1][bi_g][un_g + 3 * U];
            }
            float si = 1.f / (1.f + expf(-zi));
            float sf = 1.f / (1.f + expf(-zf));
            float so = 1.f / (1.f + expf(-zo));
            float c  = sf * creg + si * fmaxf(zg, 0.f);
            creg = c;
            float h  = so * fmaxf(c, 0.f);
            hsh[bi_g][un_g] = h;
            if (!last_only)
                hout[((size_t)(b0 + bi_g) * T_STEPS + (t0 + t)) * U + un_g] = h;
            else if (t0 + t == T_STEPS - 1)
                hout[(size_t)(b0 + bi_g) * U + un_g] = h;
        }
    }
    if (gt) {
        cst[(size_t)(b0 + bi_g) * U + un_g] = creg;
        hst[(size_t)(b0 + bi_g) * U + un_g] = hsh[bi_g][un_g];
    }
}

// Dense head: one wave per batch row. 64 ->relu-> 64 ->relu-> 32 -> 101 -> softmax
__global__ __launch_bounds__(256)
void dense_head(const float* __restrict__ h3,    // (B,64)
                const float* __restrict__ Wd1, const float* __restrict__ bd1,
                const float* __restrict__ Wd2, const float* __restrict__ bd2,
                const float* __restrict__ Wd3, const float* __restrict__ bd3,
                float* __restrict__ out)         // (B,101)
{
    __shared__ float s1[4][64];
    __shared__ float s2[4][32];
    const int w    = threadIdx.x >> 6;
    const int lane = threadIdx.x & 63;
    const int row  = blockIdx.x * 4 + w;

    float hval = h3[(size_t)row * 64 + lane];
    float a = bd1[lane];
#pragma unroll
    for (int k = 0; k < 64; ++k) {
        float hk = __shfl(hval, k, 64);
        a = fmaf(hk, Wd1[k * 64 + lane], a);
    }
    s1[w][lane] = fmaxf(a, 0.f);
    __syncthreads();

    if (lane < 32) {
        float a2 = bd2[lane];
#pragma unroll
        for (int k = 0; k < 64; ++k) a2 = fmaf(s1[w][k], Wd2[k * 32 + lane], a2);
        s2[w][lane] = fmaxf(a2, 0.f);
    }
    __syncthreads();

    float a0 = bd3[lane];
#pragma unroll
    for (int k = 0; k < 32; ++k) a0 = fmaf(s2[w][k], Wd3[k * 101 + lane], a0);
    float a1 = -INFINITY;
    if (lane < 37) {
        a1 = bd3[64 + lane];
#pragma unroll
        for (int k = 0; k < 32; ++k) a1 = fmaf(s2[w][k], Wd3[k * 101 + 64 + lane], a1);
    }

    float m = fmaxf(a0, a1);
#pragma unroll
    for (int off = 32; off > 0; off >>= 1) m = fmaxf(m, __shfl_xor(m, off, 64));
    float e0 = expf(a0 - m);
    float e1 = (lane < 37) ? expf(a1 - m) : 0.f;
    float s = e0 + e1;
#pragma unroll
    for (int off = 32; off > 0; off >>= 1) s += __shfl_xor(s, off, 64);

    out[(size_t)row * 101 + lane] = e0 / s;
    if (lane < 37) out[(size_t)row * 101 + 64 + lane] = e1 / s;
}

extern "C" void kernel_launch(void* const* d_in, const int* in_sizes, int n_in,
                              void* d_out, int out_size, void* d_ws, size_t ws_size,
                              hipStream_t stream) {
    const float* x   = (const float*)d_in[0];
    const float* W1  = (const float*)d_in[1];
    const float* U1  = (const float*)d_in[2];
    const float* b1  = (const float*)d_in[3];
    const float* W2  = (const float*)d_in[4];
    const float* U2  = (const float*)d_in[5];
    const float* b2  = (const float*)d_in[6];
    const float* W3  = (const float*)d_in[7];
    const float* U3  = (const float*)d_in[8];
    const float* b3  = (const float*)d_in[9];
    const float* Wd1 = (const float*)d_in[10];
    const float* bd1 = (const float*)d_in[11];
    const float* Wd2 = (const float*)d_in[12];
    const float* bd2 = (const float*)d_in[13];
    const float* Wd3 = (const float*)d_in[14];
    const float* bd3 = (const float*)d_in[15];

    // workspace layout (floats); peak ~160 MB
    float* xzbuf = (float*)d_ws;                      // up to 1024*60*256
    float* h1  = xzbuf + 15728640;                    // 1024*120*64
    float* h2  = h1 + 7864320;                        // 1024*120*128
    float* h3  = h2 + 15728640;                       // 1024*64
    float* c1  = h3 + 65536;
    float* hs1 = c1 + 65536;
    float* c2  = hs1 + 65536;                         // 1024*128
    float* hs2 = c2 + 131072;
    float* c3  = hs2 + 131072;
    float* hs3 = c3 + 65536;

    // Layer 1: K=132 -> 4U=256, time chunks of 60
    for (int ch = 0; ch < 2; ++ch) {
        gemm_xz<<<dim3(480, 4), 256, 0, stream>>>(x, W1, xzbuf, 256, 132, 60, ch * 60);
        lstm_rec<64, 1, 1><<<1024, 256, 0, stream>>>(xzbuf, U1, b1, h1, c1, hs1, 60, ch * 60, 0);
    }
    // Layer 2: K=64 -> 4U=512, time chunks of 30
    for (int ch = 0; ch < 4; ++ch) {
        gemm_xz<<<dim3(240, 8), 256, 0, stream>>>(h1, W2, xzbuf, 512, 64, 30, ch * 30);
        lstm_rec<128, 2, 4><<<256, 1024, 0, stream>>>(xzbuf, U2, b2, h2, c2, hs2, 30, ch * 30, 0);
    }
    // Layer 3: K=128 -> 4U=256, time chunks of 60, last hidden only
    for (int ch = 0; ch < 2; ++ch) {
        gemm_xz<<<dim3(480, 4), 256, 0, stream>>>(h2, W3, xzbuf, 256, 128, 60, ch * 60);
        lstm_rec<64, 1, 1><<<1024, 256, 0, stream>>>(xzbuf, U3, b3, h3, c3, hs3, 60, ch * 60, 1);
    }
    dense_head<<<256, 256, 0, stream>>>(h3, Wd1, bd1, Wd2, bd2, Wd3, bd3, (float*)d_out);
}

// Round 5
// 863.271 us; speedup vs baseline: 1.4914x; 1.1428x over previous
//
#include <hip/hip_runtime.h>
#include <math.h>

#define T_STEPS 120
#define BATCH   1024

typedef __attribute__((ext_vector_type(8))) short bf16x8;
typedef __attribute__((ext_vector_type(4))) float f32x4;
typedef __attribute__((ext_vector_type(4))) unsigned short us4;

// slot swizzle: maps row&15 -> 0..7, each value hit exactly twice (2-way = free)
__device__ __forceinline__ int gsw(int r) { return (r & 7) ^ ((r >> 3) & 1); }

// split f into hi (truncated bf16) + lo (RNE bf16 of remainder); f ~= hi+lo (2^-17)
// returns (hi << 16) | lo
__device__ __forceinline__ unsigned split2(float f) {
    union { float f; unsigned u; } a; a.f = f;
    unsigned hi = a.u >> 16;
    union { float f; unsigned u; } h; h.u = a.u & 0xFFFF0000u;
    union { float f; unsigned u; } b; b.f = f - h.f;
    unsigned rr = b.u + 0x7FFFu + ((b.u >> 16) & 1);
    return (hi << 16) | (rr >> 16);
}

// ---------------------------------------------------------------------------
// Split-bf16 MFMA GEMM: C[m,n] = sum_k A'[m,k]*Bw[k,n] in ~fp32 precision.
// A' row m maps to (b = m/TC, t = t0 + m%TC) of a (B,T,K) tensor.
// BM=128, BN=64, BK=64, 256 threads = 4 waves, wave tile 64x32,
// 16x16x32 bf16 MFMA x3 terms (hh, hl, lh). LDS slot-XOR swizzle.
// ---------------------------------------------------------------------------
__global__ __launch_bounds__(256, 2)
void gemm_xz_mfma(const float* __restrict__ A,   // (B, T, K)
                  const float* __restrict__ Bw,  // (K, N)
                  float* __restrict__ C,         // (B, TC, N)
                  int N, int K, int TC, int t0)
{
    constexpr int BM = 128, BN = 64, BK = 64;
    __shared__ unsigned short Ah[BM * BK], Al[BM * BK];   // [m][k] swizzled
    __shared__ unsigned short Bh[BN * BK], Bl[BN * BK];   // [n][k] (B transposed)

    const int tid  = threadIdx.x;
    const int lane = tid & 63;
    const int wv   = tid >> 6;
    const int wm   = wv & 1;             // m-half (64 rows)
    const int wn   = wv >> 1;            // n-half (32 cols)
    const int m0   = blockIdx.x * BM;
    const int n0   = blockIdx.y * BN;

    f32x4 acc[4][2] = {};

    const int ktiles = (K + BK - 1) / BK;
    for (int kt = 0; kt < ktiles; ++kt) {
        const int kb = kt * BK;
        __syncthreads();                 // prev-tile frag reads done

        // ---- stage A tile: 8 rounds x 16 rows; thread: row=rd*16+(tid>>4), f4=tid&15
        {
            const int f4   = tid & 15;
            const int sub  = (f4 & 1) * 4;
            const int k8   = f4 >> 1;
            const int kidx = kb + f4 * 4;
            const bool kok = (kidx < K);             // K % 4 == 0 always
            for (int rd = 0; rd < 8; ++rd) {
                int m  = rd * 16 + (tid >> 4);
                int gm = m0 + m;
                int b  = gm / TC;
                int tt = t0 + (gm - b * TC);
                float4 v = make_float4(0.f, 0.f, 0.f, 0.f);
                if (kok)
                    v = *reinterpret_cast<const float4*>(
                            &A[((size_t)b * T_STEPS + tt) * K + kidx]);
                unsigned px = split2(v.x), py = split2(v.y);
                unsigned pz = split2(v.z), pw = split2(v.w);
                us4 hh, ll;
                hh.x = (unsigned short)(px >> 16); ll.x = (unsigned short)px;
                hh.y = (unsigned short)(py >> 16); ll.y = (unsigned short)py;
                hh.z = (unsigned short)(pz >> 16); ll.z = (unsigned short)pz;
                hh.w = (unsigned short)(pw >> 16); ll.w = (unsigned short)pw;
                int off = m * 64 + ((k8 ^ gsw(m & 15)) * 8) + sub;
                *reinterpret_cast<us4*>(&Ah[off]) = hh;
                *reinterpret_cast<us4*>(&Al[off]) = ll;
            }
        }
        // ---- stage B tile transposed: 512 units of 8 shorts; 2 units/thread
        {
#pragma unroll
            for (int i = 0; i < 2; ++i) {
                int u  = tid + i * 256;
                int n  = u & 63;
                int k8 = u >> 6;
                unsigned short th[8], tl[8];
#pragma unroll
                for (int e = 0; e < 8; ++e) {
                    int k = kb + k8 * 8 + e;
                    float f = (k < K) ? Bw[(size_t)k * N + n0 + n] : 0.f;
                    unsigned p = split2(f);
                    th[e] = (unsigned short)(p >> 16);
                    tl[e] = (unsigned short)p;
                }
                us4 h0, h1, l0, l1;
                h0.x = th[0]; h0.y = th[1]; h0.z = th[2]; h0.w = th[3];
                h1.x = th[4]; h1.y = th[5]; h1.z = th[6]; h1.w = th[7];
                l0.x = tl[0]; l0.y = tl[1]; l0.z = tl[2]; l0.w = tl[3];
                l1.x = tl[4]; l1.y = tl[5]; l1.z = tl[6]; l1.w = tl[7];
                int off = n * 64 + ((k8 ^ gsw(n & 15)) * 8);
                *reinterpret_cast<us4*>(&Bh[off])     = h0;
                *reinterpret_cast<us4*>(&Bh[off + 4]) = h1;
                *reinterpret_cast<us4*>(&Bl[off])     = l0;
                *reinterpret_cast<us4*>(&Bl[off + 4]) = l1;
            }
        }
        __syncthreads();                 // tiles visible

        // ---- compute: 2 k-steps of 32
        const int row = lane & 15;
        const int kq  = lane >> 4;       // 0..3
        const int gr  = gsw(row);
#pragma unroll
        for (int ks = 0; ks < 2; ++ks) {
            const int k8 = ks * 4 + kq;
            bf16x8 bh[2], bl[2];
#pragma unroll
            for (int ni = 0; ni < 2; ++ni) {
                int n = wn * 32 + ni * 16 + row;
                int off = n * 64 + ((k8 ^ gr) * 8);
                bh[ni] = *reinterpret_cast<const bf16x8*>(&Bh[off]);
                bl[ni] = *reinterpret_cast<const bf16x8*>(&Bl[off]);
            }
#pragma unroll
            for (int mi = 0; mi < 4; ++mi) {
                int m = wm * 64 + mi * 16 + row;
                int off = m * 64 + ((k8 ^ gr) * 8);
                bf16x8 ah = *reinterpret_cast<const bf16x8*>(&Ah[off]);
                bf16x8 al = *reinterpret_cast<const bf16x8*>(&Al[off]);
#pragma unroll
                for (int ni = 0; ni < 2; ++ni) {
                    acc[mi][ni] = __builtin_amdgcn_mfma_f32_16x16x32_bf16(ah, bh[ni], acc[mi][ni], 0, 0, 0);
                    acc[mi][ni] = __builtin_amdgcn_mfma_f32_16x16x32_bf16(ah, bl[ni], acc[mi][ni], 0, 0, 0);
                    acc[mi][ni] = __builtin_amdgcn_mfma_f32_16x16x32_bf16(al, bh[ni], acc[mi][ni], 0, 0, 0);
                }
            }
        }
    }

    // ---- epilogue: C/D layout col = lane&15, row = (lane>>4)*4 + reg (m89)
    const int col = lane & 15;
    const int rq  = (lane >> 4) * 4;
#pragma unroll
    for (int mi = 0; mi < 4; ++mi) {
#pragma unroll
        for (int r = 0; r < 4; ++r) {
            int gm = m0 + wm * 64 + mi * 16 + rq + r;
            int b  = gm / TC;
            int tl = gm - b * TC;
#pragma unroll
            for (int ni = 0; ni < 2; ++ni) {
                int n = n0 + wn * 32 + ni * 16 + col;
                C[((size_t)b * TC + tl) * N + n] = acc[mi][ni][r];
            }
        }
    }
}

// ---------------------------------------------------------------------------
// Recurrent scan: z = xz_t + h @ Uw + b. Thread (kh, j) owns a 64-row slice
// of column j of Uw in 16 float4 registers. KSPLIT partials meet in zbuf.
// ---------------------------------------------------------------------------
template<int U, int KSPLIT, int NB>
__global__ __launch_bounds__(4 * U * KSPLIT, 4)
void lstm_rec(const float* __restrict__ xz,    // (B, TC, 4U) chunk
              const float* __restrict__ Uw,    // (U, 4U)
              const float* __restrict__ bias,  // (4U)
              float* __restrict__ hout,        // (B,T,U) or (B,U) if last_only
              float* __restrict__ cst,         // (B,U)
              float* __restrict__ hst,         // (B,U)
              int TC, int t0, int last_only)
{
    constexpr int NZ  = 4 * U;
    constexpr int KCH = U / KSPLIT;
    static_assert(KCH == 64, "weight slice must be 64 floats");

    const int tid = threadIdx.x;
    const int j   = tid & (NZ - 1);
    const int kh  = tid / NZ;
    const int b0  = blockIdx.x * NB;

    __shared__ __align__(16) float hsh[NB][U];
    __shared__ float zbuf[KSPLIT][NB][NZ];

    float4 wc[16];
#pragma unroll
    for (int q = 0; q < 16; ++q) {
        wc[q].x = Uw[(size_t)(kh * KCH + 4 * q + 0) * NZ + j];
        wc[q].y = Uw[(size_t)(kh * KCH + 4 * q + 1) * NZ + j];
        wc[q].z = Uw[(size_t)(kh * KCH + 4 * q + 2) * NZ + j];
        wc[q].w = Uw[(size_t)(kh * KCH + 4 * q + 3) * NZ + j];
    }
    const float breg = bias[j];

    const bool gt = (tid < NB * U);
    const int bi_g = tid / U;
    const int un_g = tid & (U - 1);
    float creg = 0.f;
    if (gt) {
        float h0 = 0.f;
        if (t0 != 0) {
            creg = cst[(size_t)(b0 + bi_g) * U + un_g];
            h0   = hst[(size_t)(b0 + bi_g) * U + un_g];
        }
        hsh[bi_g][un_g] = h0;
    }

    float xzv[NB];
    if (kh == 0) {
#pragma unroll
        for (int bi = 0; bi < NB; ++bi)
            xzv[bi] = xz[((size_t)(b0 + bi) * TC + 0) * NZ + j];
    }

    for (int t = 0; t < TC; ++t) {
        __syncthreads();
        float acc[NB];
#pragma unroll
        for (int bi = 0; bi < NB; ++bi)
            acc[bi] = (kh == 0) ? (breg + xzv[bi]) : 0.f;
        if (kh == 0 && t + 1 < TC) {
#pragma unroll
            for (int bi = 0; bi < NB; ++bi)
                xzv[bi] = xz[((size_t)(b0 + bi) * TC + (t + 1)) * NZ + j];
        }
#pragma unroll
        for (int q = 0; q < 16; ++q) {
#pragma unroll
            for (int bi = 0; bi < NB; ++bi) {
                float4 h4 = *reinterpret_cast<const float4*>(&hsh[bi][kh * KCH + 4 * q]);
                acc[bi] = fmaf(h4.x, wc[q].x, acc[bi]);
                acc[bi] = fmaf(h4.y, wc[q].y, acc[bi]);
                acc[bi] = fmaf(h4.z, wc[q].z, acc[bi]);
                acc[bi] = fmaf(h4.w, wc[q].w, acc[bi]);
            }
        }
#pragma unroll
        for (int bi = 0; bi < NB; ++bi) zbuf[kh][bi][j] = acc[bi];
        __syncthreads();
        if (gt) {
            float zi = zbuf[0][bi_g][un_g];
            float zf = zbuf[0][bi_g][un_g + U];
            float zg = zbuf[0][bi_g][un_g + 2 * U];
            float zo = zbuf[0][bi_g][un_g + 3 * U];
            if constexpr (KSPLIT == 2) {
                zi += zbuf[1][bi_g][un_g];
                zf += zbuf[1][bi_g][un_g + U];
                zg += zbuf[1][bi_g][un_g + 2 * U];
                zo += zbuf[1][bi_g][un_g + 3 * U];
            }
            float si = 1.f / (1.f + expf(-zi));
            float sf = 1.f / (1.f + expf(-zf));
            float so = 1.f / (1.f + expf(-zo));
            float c  = sf * creg + si * fmaxf(zg, 0.f);
            creg = c;
            float h  = so * fmaxf(c, 0.f);
            hsh[bi_g][un_g] = h;
            if (!last_only)
                hout[((size_t)(b0 + bi_g) * T_STEPS + (t0 + t)) * U + un_g] = h;
            else if (t0 + t == T_STEPS - 1)
                hout[(size_t)(b0 + bi_g) * U + un_g] = h;
        }
    }
    if (gt) {
        cst[(size_t)(b0 + bi_g) * U + un_g] = creg;
        hst[(size_t)(b0 + bi_g) * U + un_g] = hsh[bi_g][un_g];
    }
}

// Dense head: one wave per batch row. 64 ->relu-> 64 ->relu-> 32 -> 101 -> softmax
__global__ __launch_bounds__(256)
void dense_head(const float* __restrict__ h3,    // (B,64)
                const float* __restrict__ Wd1, const float* __restrict__ bd1,
                const float* __restrict__ Wd2, const float* __restrict__ bd2,
                const float* __restrict__ Wd3, const float* __restrict__ bd3,
                float* __restrict__ out)         // (B,101)
{
    __shared__ float s1[4][64];
    __shared__ float s2[4][32];
    const int w    = threadIdx.x >> 6;
    const int lane = threadIdx.x & 63;
    const int row  = blockIdx.x * 4 + w;

    float hval = h3[(size_t)row * 64 + lane];
    float a = bd1[lane];
#pragma unroll
    for (int k = 0; k < 64; ++k) {
        float hk = __shfl(hval, k, 64);
        a = fmaf(hk, Wd1[k * 64 + lane], a);
    }
    s1[w][lane] = fmaxf(a, 0.f);
    __syncthreads();

    if (lane < 32) {
        float a2 = bd2[lane];
#pragma unroll
        for (int k = 0; k < 64; ++k) a2 = fmaf(s1[w][k], Wd2[k * 32 + lane], a2);
        s2[w][lane] = fmaxf(a2, 0.f);
    }
    __syncthreads();

    float a0 = bd3[lane];
#pragma unroll
    for (int k = 0; k < 32; ++k) a0 = fmaf(s2[w][k], Wd3[k * 101 + lane], a0);
    float a1 = -INFINITY;
    if (lane < 37) {
        a1 = bd3[64 + lane];
#pragma unroll
        for (int k = 0; k < 32; ++k) a1 = fmaf(s2[w][k], Wd3[k * 101 + 64 + lane], a1);
    }

    float m = fmaxf(a0, a1);
#pragma unroll
    for (int off = 32; off > 0; off >>= 1) m = fmaxf(m, __shfl_xor(m, off, 64));
    float e0 = expf(a0 - m);
    float e1 = (lane < 37) ? expf(a1 - m) : 0.f;
    float s = e0 + e1;
#pragma unroll
    for (int off = 32; off > 0; off >>= 1) s += __shfl_xor(s, off, 64);

    out[(size_t)row * 101 + lane] = e0 / s;
    if (lane < 37) out[(size_t)row * 101 + 64 + lane] = e1 / s;
}

extern "C" void kernel_launch(void* const* d_in, const int* in_sizes, int n_in,
                              void* d_out, int out_size, void* d_ws, size_t ws_size,
                              hipStream_t stream) {
    const float* x   = (const float*)d_in[0];
    const float* W1  = (const float*)d_in[1];
    const float* U1  = (const float*)d_in[2];
    const float* b1  = (const float*)d_in[3];
    const float* W2  = (const float*)d_in[4];
    const float* U2  = (const float*)d_in[5];
    const float* b2  = (const float*)d_in[6];
    const float* W3  = (const float*)d_in[7];
    const float* U3  = (const float*)d_in[8];
    const float* b3  = (const float*)d_in[9];
    const float* Wd1 = (const float*)d_in[10];
    const float* bd1 = (const float*)d_in[11];
    const float* Wd2 = (const float*)d_in[12];
    const float* bd2 = (const float*)d_in[13];
    const float* Wd3 = (const float*)d_in[14];
    const float* bd3 = (const float*)d_in[15];

    // workspace layout (floats); peak ~160 MB
    float* xzbuf = (float*)d_ws;                      // up to 1024*60*256
    float* h1  = xzbuf + 15728640;                    // 1024*120*64
    float* h2  = h1 + 7864320;                        // 1024*120*128
    float* h3  = h2 + 15728640;                       // 1024*64
    float* c1  = h3 + 65536;
    float* hs1 = c1 + 65536;
    float* c2  = hs1 + 65536;                         // 1024*128
    float* hs2 = c2 + 131072;
    float* c3  = hs2 + 131072;
    float* hs3 = c3 + 65536;

    // Layer 1: K=132 -> 4U=256, time chunks of 60
    for (int ch = 0; ch < 2; ++ch) {
        gemm_xz_mfma<<<dim3(480, 4), 256, 0, stream>>>(x, W1, xzbuf, 256, 132, 60, ch * 60);
        lstm_rec<64, 1, 1><<<1024, 256, 0, stream>>>(xzbuf, U1, b1, h1, c1, hs1, 60, ch * 60, 0);
    }
    // Layer 2: K=64 -> 4U=512, time chunks of 30
    for (int ch = 0; ch < 4; ++ch) {
        gemm_xz_mfma<<<dim3(240, 8), 256, 0, stream>>>(h1, W2, xzbuf, 512, 64, 30, ch * 30);
        lstm_rec<128, 2, 4><<<256, 1024, 0, stream>>>(xzbuf, U2, b2, h2, c2, hs2, 30, ch * 30, 0);
    }
    // Layer 3: K=128 -> 4U=256, time chunks of 60, last hidden only
    for (int ch = 0; ch < 2; ++ch) {
        gemm_xz_mfma<<<dim3(480, 4), 256, 0, stream>>>(h2, W3, xzbuf, 256, 128, 60, ch * 60);
        lstm_rec<64, 1, 1><<<1024, 256, 0, stream>>>(xzbuf, U3, b3, h3, c3, hs3, 60, ch * 60, 1);
    }
    dense_head<<<256, 256, 0, stream>>>(h3, Wd1, bd1, Wd2, bd2, Wd3, bd3, (float*)d_out);
}

// Round 6
// 797.498 us; speedup vs baseline: 1.6144x; 1.0825x over previous
//
#include <hip/hip_runtime.h>
#include <math.h>

#define T_STEPS 120
#define BATCH   1024

typedef __attribute__((ext_vector_type(8))) short bf16x8;
typedef __attribute__((ext_vector_type(4))) float f32x4;
typedef __attribute__((ext_vector_type(4))) unsigned short us4;

// slot swizzle for GEMM LDS: maps row&15 -> 0..7, each value hit twice (2-way = free)
__device__ __forceinline__ int gsw(int r) { return (r & 7) ^ ((r >> 3) & 1); }

// split f into hi (truncated bf16) + lo (RNE bf16 of remainder); f ~= hi+lo (2^-17)
// returns (hi << 16) | lo
__device__ __forceinline__ unsigned split2(float f) {
    union { float f; unsigned u; } a; a.f = f;
    unsigned hi = a.u >> 16;
    union { float f; unsigned u; } h; h.u = a.u & 0xFFFF0000u;
    union { float f; unsigned u; } b; b.f = f - h.f;
    unsigned rr = b.u + 0x7FFFu + ((b.u >> 16) & 1);
    return (hi << 16) | (rr >> 16);
}

__device__ __forceinline__ float fast_sigmoid(float x) {
    float e = __expf(-x);
    return __builtin_amdgcn_rcpf(1.f + e);
}

// ---------------------------------------------------------------------------
// Split-bf16 MFMA GEMM (unchanged from round 5, proven): C = A' @ Bw
// ---------------------------------------------------------------------------
__global__ __launch_bounds__(256, 2)
void gemm_xz_mfma(const float* __restrict__ A,   // (B, T, K)
                  const float* __restrict__ Bw,  // (K, N)
                  float* __restrict__ C,         // (B, TC, N)
                  int N, int K, int TC, int t0)
{
    constexpr int BM = 128, BN = 64, BK = 64;
    __shared__ unsigned short Ah[BM * BK], Al[BM * BK];   // [m][k] swizzled
    __shared__ unsigned short Bh[BN * BK], Bl[BN * BK];   // [n][k] (B transposed)

    const int tid  = threadIdx.x;
    const int lane = tid & 63;
    const int wv   = tid >> 6;
    const int wm   = wv & 1;
    const int wn   = wv >> 1;
    const int m0   = blockIdx.x * BM;
    const int n0   = blockIdx.y * BN;

    f32x4 acc[4][2] = {};

    const int ktiles = (K + BK - 1) / BK;
    for (int kt = 0; kt < ktiles; ++kt) {
        const int kb = kt * BK;
        __syncthreads();

        {
            const int f4   = tid & 15;
            const int sub  = (f4 & 1) * 4;
            const int k8   = f4 >> 1;
            const int kidx = kb + f4 * 4;
            const bool kok = (kidx < K);
            for (int rd = 0; rd < 8; ++rd) {
                int m  = rd * 16 + (tid >> 4);
                int gm = m0 + m;
                int b  = gm / TC;
                int tt = t0 + (gm - b * TC);
                float4 v = make_float4(0.f, 0.f, 0.f, 0.f);
                if (kok)
                    v = *reinterpret_cast<const float4*>(
                            &A[((size_t)b * T_STEPS + tt) * K + kidx]);
                unsigned px = split2(v.x), py = split2(v.y);
                unsigned pz = split2(v.z), pw = split2(v.w);
                us4 hh, ll;
                hh.x = (unsigned short)(px >> 16); ll.x = (unsigned short)px;
                hh.y = (unsigned short)(py >> 16); ll.y = (unsigned short)py;
                hh.z = (unsigned short)(pz >> 16); ll.z = (unsigned short)pz;
                hh.w = (unsigned short)(pw >> 16); ll.w = (unsigned short)pw;
                int off = m * 64 + ((k8 ^ gsw(m & 15)) * 8) + sub;
                *reinterpret_cast<us4*>(&Ah[off]) = hh;
                *reinterpret_cast<us4*>(&Al[off]) = ll;
            }
        }
        {
#pragma unroll
            for (int i = 0; i < 2; ++i) {
                int u  = tid + i * 256;
                int n  = u & 63;
                int k8 = u >> 6;
                unsigned short th[8], tl[8];
#pragma unroll
                for (int e = 0; e < 8; ++e) {
                    int k = kb + k8 * 8 + e;
                    float f = (k < K) ? Bw[(size_t)k * N + n0 + n] : 0.f;
                    unsigned p = split2(f);
                    th[e] = (unsigned short)(p >> 16);
                    tl[e] = (unsigned short)p;
                }
                us4 h0, h1, l0, l1;
                h0.x = th[0]; h0.y = th[1]; h0.z = th[2]; h0.w = th[3];
                h1.x = th[4]; h1.y = th[5]; h1.z = th[6]; h1.w = th[7];
                l0.x = tl[0]; l0.y = tl[1]; l0.z = tl[2]; l0.w = tl[3];
                l1.x = tl[4]; l1.y = tl[5]; l1.z = tl[6]; l1.w = tl[7];
                int off = n * 64 + ((k8 ^ gsw(n & 15)) * 8);
                *reinterpret_cast<us4*>(&Bh[off])     = h0;
                *reinterpret_cast<us4*>(&Bh[off + 4]) = h1;
                *reinterpret_cast<us4*>(&Bl[off])     = l0;
                *reinterpret_cast<us4*>(&Bl[off + 4]) = l1;
            }
        }
        __syncthreads();

        const int row = lane & 15;
        const int kq  = lane >> 4;
        const int gr  = gsw(row);
#pragma unroll
        for (int ks = 0; ks < 2; ++ks) {
            const int k8 = ks * 4 + kq;
            bf16x8 bh[2], bl[2];
#pragma unroll
            for (int ni = 0; ni < 2; ++ni) {
                int n = wn * 32 + ni * 16 + row;
                int off = n * 64 + ((k8 ^ gr) * 8);
                bh[ni] = *reinterpret_cast<const bf16x8*>(&Bh[off]);
                bl[ni] = *reinterpret_cast<const bf16x8*>(&Bl[off]);
            }
#pragma unroll
            for (int mi = 0; mi < 4; ++mi) {
                int m = wm * 64 + mi * 16 + row;
                int off = m * 64 + ((k8 ^ gr) * 8);
                bf16x8 ah = *reinterpret_cast<const bf16x8*>(&Ah[off]);
                bf16x8 al = *reinterpret_cast<const bf16x8*>(&Al[off]);
#pragma unroll
                for (int ni = 0; ni < 2; ++ni) {
                    acc[mi][ni] = __builtin_amdgcn_mfma_f32_16x16x32_bf16(ah, bh[ni], acc[mi][ni], 0, 0, 0);
                    acc[mi][ni] = __builtin_amdgcn_mfma_f32_16x16x32_bf16(ah, bl[ni], acc[mi][ni], 0, 0, 0);
                    acc[mi][ni] = __builtin_amdgcn_mfma_f32_16x16x32_bf16(al, bh[ni], acc[mi][ni], 0, 0, 0);
                }
            }
        }
    }

    const int col = lane & 15;
    const int rq  = (lane >> 4) * 4;
#pragma unroll
    for (int mi = 0; mi < 4; ++mi) {
#pragma unroll
        for (int r = 0; r < 4; ++r) {
            int gm = m0 + wm * 64 + mi * 16 + rq + r;
            int b  = gm / TC;
            int tl = gm - b * TC;
#pragma unroll
            for (int ni = 0; ni < 2; ++ni) {
                int n = n0 + wn * 32 + ni * 16 + col;
                C[((size_t)b * TC + tl) * N + n] = acc[mi][ni][r];
            }
        }
    }
}

// ---------------------------------------------------------------------------
// MFMA recurrent scan. Block = 16 batch rows, grid = 64. NW waves (NZ/64).
// Wave `wid` owns z-columns { p*U + wid*16 + ln : p=0..3 } -> i,f,g,o of the
// SAME (batch,unit) land in the same lane; gates combine in-register.
// U-weights pre-split to bf16 hi/lo fragments in registers (loaded once).
// h lives in LDS as packed (hi16|lo16) u32, XOR-swizzled, double-buffered.
// One barrier per step. z = xz_t + b + h @ U via 3-term split-bf16 MFMA.
// ---------------------------------------------------------------------------
template<int U, int NW>
__global__ __launch_bounds__(NW * 64, 2)
void lstm_rec_mfma(const float* __restrict__ xz,    // (B, TC, 4U) chunk
                   const float* __restrict__ Uw,    // (U, 4U)
                   const float* __restrict__ bias,  // (4U)
                   float* __restrict__ hout,        // (B,T,U) or (B,U)
                   float* __restrict__ cst,         // (B,U)
                   float* __restrict__ hst,         // (B,U)
                   int TC, int t0, int last_only)
{
    constexpr int NZ = 4 * U;
    constexpr int KT = U / 32;          // k-tiles of 32
    constexpr int NB = 16;              // batch rows per block (MFMA M)
    static_assert(NW * 16 == U, "waves cover all units");

    __shared__ unsigned hsh[2][NB][U];  // packed (hi|lo) h, swizzled cols

#define SWZ(b, c) ((c) ^ (((b) & (U / 8 - 1)) << 3))

    const int tid  = threadIdx.x;
    const int lane = tid & 63;
    const int wid  = tid >> 6;
    const int ln   = lane & 15;
    const int lq   = lane >> 4;         // 0..3
    const int b0   = blockIdx.x * NB;
    const int unit = wid * 16 + ln;

    // ---- one-time: weight fragments into registers (pre-split) ----
    bf16x8 bwh[4][KT], bwl[4][KT];
#pragma unroll
    for (int p = 0; p < 4; ++p)
#pragma unroll
        for (int kt = 0; kt < KT; ++kt) {
#pragma unroll
            for (int e = 0; e < 8; ++e) {
                int k = kt * 32 + lq * 8 + e;
                unsigned s = split2(Uw[(size_t)k * NZ + p * U + unit]);
                bwh[p][kt][e] = (short)(s >> 16);
                bwl[p][kt][e] = (short)(s & 0xFFFFu);
            }
        }
    float breg[4];
#pragma unroll
    for (int p = 0; p < 4; ++p) breg[p] = bias[p * U + unit];

    // ---- state init: c in regs, h into LDS (each lane owns 4 batch rows) ----
    float creg[4], hlast[4];
#pragma unroll
    for (int r = 0; r < 4; ++r) {
        int br = lq * 4 + r;
        float c0 = 0.f, h0 = 0.f;
        if (t0 != 0) {
            c0 = cst[(size_t)(b0 + br) * U + unit];
            h0 = hst[(size_t)(b0 + br) * U + unit];
        }
        creg[r] = c0; hlast[r] = h0;
        hsh[0][br][SWZ(br, unit)] = split2(h0);
    }

    // prefetch xz for t=0
    float xzv[4][4];    // [p][r]
#pragma unroll
    for (int p = 0; p < 4; ++p)
#pragma unroll
        for (int r = 0; r < 4; ++r)
            xzv[p][r] = xz[((size_t)(b0 + lq * 4 + r) * TC + 0) * NZ + p * U + unit];

    __syncthreads();

    int cur = 0;
    for (int t = 0; t < TC; ++t) {
        // ---- A-frags: h of 16 batches, this lane: batch=ln, k=kt*32+lq*8+e ----
        bf16x8 ah[KT], al[KT];
#pragma unroll
        for (int kt = 0; kt < KT; ++kt) {
            const unsigned* pa = &hsh[cur][ln][SWZ(ln, kt * 32 + lq * 8)];
            uint4 u0 = *reinterpret_cast<const uint4*>(pa);
            uint4 u1 = *reinterpret_cast<const uint4*>(pa + 4);
            unsigned uu[8] = {u0.x, u0.y, u0.z, u0.w, u1.x, u1.y, u1.z, u1.w};
#pragma unroll
            for (int e = 0; e < 8; ++e) {
                ah[kt][e] = (short)(uu[e] >> 16);
                al[kt][e] = (short)(uu[e] & 0xFFFFu);
            }
        }

        // ---- acc init = xz + bias (lane layout == D layout) ----
        f32x4 acc[4];
#pragma unroll
        for (int p = 0; p < 4; ++p)
#pragma unroll
            for (int r = 0; r < 4; ++r)
                acc[p][r] = xzv[p][r] + breg[p];

        // prefetch next xz under the MFMAs
        if (t + 1 < TC) {
#pragma unroll
            for (int p = 0; p < 4; ++p)
#pragma unroll
                for (int r = 0; r < 4; ++r)
                    xzv[p][r] = xz[((size_t)(b0 + lq * 4 + r) * TC + (t + 1)) * NZ + p * U + unit];
        }

        // ---- z += h @ U (3-term split) ----
#pragma unroll
        for (int kt = 0; kt < KT; ++kt)
#pragma unroll
            for (int p = 0; p < 4; ++p) {
                acc[p] = __builtin_amdgcn_mfma_f32_16x16x32_bf16(ah[kt], bwh[p][kt], acc[p], 0, 0, 0);
                acc[p] = __builtin_amdgcn_mfma_f32_16x16x32_bf16(ah[kt], bwl[p][kt], acc[p], 0, 0, 0);
                acc[p] = __builtin_amdgcn_mfma_f32_16x16x32_bf16(al[kt], bwh[p][kt], acc[p], 0, 0, 0);
            }

        // ---- gates, state update, h write ----
#pragma unroll
        for (int r = 0; r < 4; ++r) {
            float si = fast_sigmoid(acc[0][r]);
            float sf = fast_sigmoid(acc[1][r]);
            float g  = fmaxf(acc[2][r], 0.f);
            float so = fast_sigmoid(acc[3][r]);
            float c  = sf * creg[r] + si * g;
            creg[r] = c;
            float h = so * fmaxf(c, 0.f);
            hlast[r] = h;
            int br = lq * 4 + r;
            hsh[cur ^ 1][br][SWZ(br, unit)] = split2(h);
            if (!last_only)
                hout[((size_t)(b0 + br) * T_STEPS + (t0 + t)) * U + unit] = h;
            else if (t0 + t == T_STEPS - 1)
                hout[(size_t)(b0 + br) * U + unit] = h;
        }
        __syncthreads();
        cur ^= 1;
    }

    // ---- persist state for next chunk ----
#pragma unroll
    for (int r = 0; r < 4; ++r) {
        int br = lq * 4 + r;
        cst[(size_t)(b0 + br) * U + unit] = creg[r];
        hst[(size_t)(b0 + br) * U + unit] = hlast[r];
    }
#undef SWZ
}

// Dense head: one wave per batch row. 64 ->relu-> 64 ->relu-> 32 -> 101 -> softmax
__global__ __launch_bounds__(256)
void dense_head(const float* __restrict__ h3,    // (B,64)
                const float* __restrict__ Wd1, const float* __restrict__ bd1,
                const float* __restrict__ Wd2, const float* __restrict__ bd2,
                const float* __restrict__ Wd3, const float* __restrict__ bd3,
                float* __restrict__ out)         // (B,101)
{
    __shared__ float s1[4][64];
    __shared__ float s2[4][32];
    const int w    = threadIdx.x >> 6;
    const int lane = threadIdx.x & 63;
    const int row  = blockIdx.x * 4 + w;

    float hval = h3[(size_t)row * 64 + lane];
    float a = bd1[lane];
#pragma unroll
    for (int k = 0; k < 64; ++k) {
        float hk = __shfl(hval, k, 64);
        a = fmaf(hk, Wd1[k * 64 + lane], a);
    }
    s1[w][lane] = fmaxf(a, 0.f);
    __syncthreads();

    if (lane < 32) {
        float a2 = bd2[lane];
#pragma unroll
        for (int k = 0; k < 64; ++k) a2 = fmaf(s1[w][k], Wd2[k * 32 + lane], a2);
        s2[w][lane] = fmaxf(a2, 0.f);
    }
    __syncthreads();

    float a0 = bd3[lane];
#pragma unroll
    for (int k = 0; k < 32; ++k) a0 = fmaf(s2[w][k], Wd3[k * 101 + lane], a0);
    float a1 = -INFINITY;
    if (lane < 37) {
        a1 = bd3[64 + lane];
#pragma unroll
        for (int k = 0; k < 32; ++k) a1 = fmaf(s2[w][k], Wd3[k * 101 + 64 + lane], a1);
    }

    float m = fmaxf(a0, a1);
#pragma unroll
    for (int off = 32; off > 0; off >>= 1) m = fmaxf(m, __shfl_xor(m, off, 64));
    float e0 = expf(a0 - m);
    float e1 = (lane < 37) ? expf(a1 - m) : 0.f;
    float s = e0 + e1;
#pragma unroll
    for (int off = 32; off > 0; off >>= 1) s += __shfl_xor(s, off, 64);

    out[(size_t)row * 101 + lane] = e0 / s;
    if (lane < 37) out[(size_t)row * 101 + 64 + lane] = e1 / s;
}

extern "C" void kernel_launch(void* const* d_in, const int* in_sizes, int n_in,
                              void* d_out, int out_size, void* d_ws, size_t ws_size,
                              hipStream_t stream) {
    const float* x   = (const float*)d_in[0];
    const float* W1  = (const float*)d_in[1];
    const float* U1  = (const float*)d_in[2];
    const float* b1  = (const float*)d_in[3];
    const float* W2  = (const float*)d_in[4];
    const float* U2  = (const float*)d_in[5];
    const float* b2  = (const float*)d_in[6];
    const float* W3  = (const float*)d_in[7];
    const float* U3  = (const float*)d_in[8];
    const float* b3  = (const float*)d_in[9];
    const float* Wd1 = (const float*)d_in[10];
    const float* bd1 = (const float*)d_in[11];
    const float* Wd2 = (const float*)d_in[12];
    const float* bd2 = (const float*)d_in[13];
    const float* Wd3 = (const float*)d_in[14];
    const float* bd3 = (const float*)d_in[15];

    // workspace layout (floats); peak ~160 MB
    float* xzbuf = (float*)d_ws;                      // up to 1024*60*256
    float* h1  = xzbuf + 15728640;                    // 1024*120*64
    float* h2  = h1 + 7864320;                        // 1024*120*128
    float* h3  = h2 + 15728640;                       // 1024*64
    float* c1  = h3 + 65536;
    float* hs1 = c1 + 65536;
    float* c2  = hs1 + 65536;                         // 1024*128
    float* hs2 = c2 + 131072;
    float* c3  = hs2 + 131072;
    float* hs3 = c3 + 65536;

    // Layer 1: K=132 -> 4U=256, time chunks of 60
    for (int ch = 0; ch < 2; ++ch) {
        gemm_xz_mfma<<<dim3(480, 4), 256, 0, stream>>>(x, W1, xzbuf, 256, 132, 60, ch * 60);
        lstm_rec_mfma<64, 4><<<64, 256, 0, stream>>>(xzbuf, U1, b1, h1, c1, hs1, 60, ch * 60, 0);
    }
    // Layer 2: K=64 -> 4U=512, time chunks of 30
    for (int ch = 0; ch < 4; ++ch) {
        gemm_xz_mfma<<<dim3(240, 8), 256, 0, stream>>>(h1, W2, xzbuf, 512, 64, 30, ch * 30);
        lstm_rec_mfma<128, 8><<<64, 512, 0, stream>>>(xzbuf, U2, b2, h2, c2, hs2, 30, ch * 30, 0);
    }
    // Layer 3: K=128 -> 4U=256, time chunks of 60, last hidden only
    for (int ch = 0; ch < 2; ++ch) {
        gemm_xz_mfma<<<dim3(480, 4), 256, 0, stream>>>(h2, W3, xzbuf, 256, 128, 60, ch * 60);
        lstm_rec_mfma<64, 4><<<64, 256, 0, stream>>>(xzbuf, U3, b3, h3, c3, hs3, 60, ch * 60, 1);
    }
    dense_head<<<256, 256, 0, stream>>>(h3, Wd1, bd1, Wd2, bd2, Wd3, bd3, (float*)d_out);
}